// Round 4
// baseline (170.036 us; speedup 1.0000x reference)
//
#include <hip/hip_runtime.h>
#include <math.h>

#define TOPK  20
#define NROW  4096
#define DDIM  256
#define NB    4
#define NCHUNK 16               // float4 chunks per lane (64 values/lane)

#define AWPB   2                // kernel A: waves (rows) per block
#define ABLOCK (AWPB * 64)
#define BBLOCK 256              // kernel B: 4 waves = 4 batches of one row

__device__ __forceinline__ void wave_lds_fence() {
    asm volatile("s_waitcnt lgkmcnt(0)" ::: "memory");
}

__device__ __forceinline__ bool lex_gt(float av, int ai, float bv, int bi) {
    return (av > bv) || (av == bv && ai < bi);   // (value desc, index asc)
}

// bitonic sort of 64 (v,i) pairs across lanes, descending by lex key
__device__ __forceinline__ void bitonic64_desc(float& v, int& i, int lane) {
#pragma unroll
    for (int k = 2; k <= 64; k <<= 1) {
#pragma unroll
        for (int j = k >> 1; j > 0; j >>= 1) {
            float pv = __shfl_xor(v, j, 64);
            int   pi = __shfl_xor(i, j, 64);
            bool takeBig = ((lane & k) == 0) == ((lane & j) == 0);
            bool pBig = lex_gt(pv, pi, v, i);
            if (takeBig == pBig) { v = pv; i = pi; }
        }
    }
}

// ---------------- Kernel A: per-row softmax top-20 selection ----------------
// One wave per row; row resident in 64 VGPRs; writes (w[20], idx[20]) to ws.
__global__ __launch_bounds__(ABLOCK, 4) void topk_select(
    const float* __restrict__ mem,
    float* __restrict__ ws_w,
    int*   __restrict__ ws_i)
{
    __shared__ float cand_v[AWPB][64];
    __shared__ int   cand_i[AWPB][64];
    const int wave = threadIdx.x >> 6;
    const int lane = threadIdx.x & 63;
    const int n    = blockIdx.x * AWPB + wave;

    // stage full row into registers: lane holds elements 4*lane+256*j+c
    const float4* mrow = (const float4*)(mem + (size_t)n * NROW);
    float4 v4[NCHUNK];
#pragma unroll
    for (int j = 0; j < NCHUNK; ++j) v4[j] = mrow[lane + 64 * j];

    // per-lane top-1 (ascending index order -> strict > keeps lowest idx)
    float bv = -INFINITY; int bi = 0x7fffffff;
#pragma unroll
    for (int j = 0; j < NCHUNK; ++j) {
        const int base = 4 * lane + 256 * j;
        if (v4[j].x > bv) { bv = v4[j].x; bi = base + 0; }
        if (v4[j].y > bv) { bv = v4[j].y; bi = base + 1; }
        if (v4[j].z > bv) { bv = v4[j].z; bi = base + 2; }
        if (v4[j].w > bv) { bv = v4[j].w; bi = base + 3; }
    }

    // sort lane maxima: sorted[0] = row max, sorted[19] = threshold tau
    float sv = bv; int si = bi;
    bitonic64_desc(sv, si, lane);
    const float rowmax = __shfl(sv, 0, 64);
    const float tv     = __shfl(sv, 19, 64);
    const int   ti     = __shfl(si, 19, 64);

    // softmax denominator (from registers)
    float lsum = 0.f;
#pragma unroll
    for (int j = 0; j < NCHUNK; ++j) {
        lsum += __expf(v4[j].x - rowmax) + __expf(v4[j].y - rowmax)
              + __expf(v4[j].z - rowmax) + __expf(v4[j].w - rowmax);
    }
#pragma unroll
    for (int o = 32; o > 0; o >>= 1) lsum += __shfl_xor(lsum, o, 64);
    const float inv_denom = 1.0f / lsum;

    // count candidates >=lex (tv, ti); guaranteed >= 20 total
    int cnt = 0;
#pragma unroll
    for (int j = 0; j < NCHUNK; ++j) {
        const int base = 4 * lane + 256 * j;
        cnt += (v4[j].x > tv) || (v4[j].x == tv && (base + 0) <= ti);
        cnt += (v4[j].y > tv) || (v4[j].y == tv && (base + 1) <= ti);
        cnt += (v4[j].z > tv) || (v4[j].z == tv && (base + 2) <= ti);
        cnt += (v4[j].w > tv) || (v4[j].w == tv && (base + 3) <= ti);
    }
    int incl = cnt;
#pragma unroll
    for (int o = 1; o < 64; o <<= 1) {
        int t = __shfl_up(incl, o, 64);
        if (lane >= o) incl += t;
    }
    const int total = __builtin_amdgcn_readfirstlane(__shfl(incl, 63, 64));

    float* gw = ws_w + (size_t)n * TOPK;
    int*   gi = ws_i + (size_t)n * TOPK;

    if (total <= 64) {
        // FAST PATH: compact candidates to LDS (prefix-sum offsets), sort once
        int off = incl - cnt;
#pragma unroll
        for (int j = 0; j < NCHUNK; ++j) {
            const int base = 4 * lane + 256 * j;
            const float4 q = v4[j];
            if ((q.x > tv) || (q.x == tv && (base + 0) <= ti)) { cand_v[wave][off] = q.x; cand_i[wave][off] = base + 0; ++off; }
            if ((q.y > tv) || (q.y == tv && (base + 1) <= ti)) { cand_v[wave][off] = q.y; cand_i[wave][off] = base + 1; ++off; }
            if ((q.z > tv) || (q.z == tv && (base + 2) <= ti)) { cand_v[wave][off] = q.z; cand_i[wave][off] = base + 2; ++off; }
            if ((q.w > tv) || (q.w == tv && (base + 3) <= ti)) { cand_v[wave][off] = q.w; cand_i[wave][off] = base + 3; ++off; }
        }
        wave_lds_fence();
        float cv = -INFINITY; int ci = 0x7fffffff;
        if (lane < total) { cv = cand_v[wave][lane]; ci = cand_i[wave][lane]; }
        bitonic64_desc(cv, ci, lane);
        if (lane < TOPK) {
            gw[lane] = __expf(cv - rowmax) * inv_denom;
            gi[lane] = ci;
        }
    } else {
        // SLOW PATH (p ~ 0): 20 rounds of wave argmax extraction from regs
        unsigned long long dead = 0;
        float cv = bv; int ci = bi;
        for (int r = 0; r < TOPK; ++r) {
            float wv = cv; int wi = ci;
#pragma unroll
            for (int o = 32; o > 0; o >>= 1) {
                float ov = __shfl_xor(wv, o, 64);
                int   oi = __shfl_xor(wi, o, 64);
                if (lex_gt(ov, oi, wv, wi)) { wv = ov; wi = oi; }
            }
            if (lane == 0) {
                gw[r] = __expf(wv - rowmax) * inv_denom;
                gi[r] = wi;
            }
            if (ci == wi) {   // unique owner kills its element and rescans
                const int e = 4 * ((wi >> 8) & 15) + (wi & 3);
                dead |= (1ull << e);
                cv = -INFINITY; ci = 0x7fffffff;
#pragma unroll
                for (int j = 0; j < NCHUNK; ++j) {
                    const int base = 4 * lane + 256 * j;
                    if (!((dead >> (4 * j + 0)) & 1) && v4[j].x > cv) { cv = v4[j].x; ci = base + 0; }
                    if (!((dead >> (4 * j + 1)) & 1) && v4[j].y > cv) { cv = v4[j].y; ci = base + 1; }
                    if (!((dead >> (4 * j + 2)) & 1) && v4[j].z > cv) { cv = v4[j].z; ci = base + 2; }
                    if (!((dead >> (4 * j + 3)) & 1) && v4[j].w > cv) { cv = v4[j].w; ci = base + 3; }
                }
            }
        }
    }
}

// ---------------- Kernel B: gather epilogue ----------------
// Block = one row n, 4 waves = 4 batches. Pure streaming + gather.
__global__ __launch_bounds__(BBLOCK, 4) void gather_epilogue(
    const float* __restrict__ src1,
    const float* __restrict__ src2,
    const float* __restrict__ ws_w,
    const int*   __restrict__ ws_i,
    float* __restrict__ out)
{
    const int n    = blockIdx.x;
    const int b    = threadIdx.x >> 6;
    const int lane = threadIdx.x & 63;

    // uniform (per-block) weight/index reads -> scalarizable
    const float* gw = ws_w + (size_t)n * TOPK;
    const int*   gi = ws_i + (size_t)n * TOPK;
    float wk[TOPK]; int ik[TOPK];
#pragma unroll
    for (int k = 0; k < TOPK; ++k) { wk[k] = gw[k]; ik[k] = gi[k]; }

    const float4* s1 = (const float4*)src1;
    const float4* s2 = (const float4*)src2;
    float4*       o4 = (float4*)out;

    const size_t rowbase = ((size_t)b * NROW + n) * (DDIM / 4) + lane;
    const size_t bbase   = (size_t)b * NROW * (DDIM / 4) + lane;
    float4 acc = s1[rowbase];
#pragma unroll
    for (int k = 0; k < TOPK; ++k) {
        const float4 g = s2[bbase + (size_t)ik[k] * (DDIM / 4)];
        acc.x = fmaf(wk[k], g.x, acc.x);
        acc.y = fmaf(wk[k], g.y, acc.y);
        acc.z = fmaf(wk[k], g.z, acc.z);
        acc.w = fmaf(wk[k], g.w, acc.w);
    }
    o4[rowbase] = acc;
}

extern "C" void kernel_launch(void* const* d_in, const int* in_sizes, int n_in,
                              void* d_out, int out_size, void* d_ws, size_t ws_size,
                              hipStream_t stream) {
    const float* src1 = (const float*)d_in[0];   // [4, 4096, 256] f32
    const float* src2 = (const float*)d_in[1];   // [4, 4096, 256] f32
    const float* mem  = (const float*)d_in[2];   // [4096, 4096] f32
    float* out = (float*)d_out;                  // [4, 4096, 256] f32

    float* ws_w = (float*)d_ws;                  // 4096*20 floats = 320 KB
    int*   ws_i = (int*)d_ws + (size_t)NROW * TOPK;  // next 320 KB

    topk_select<<<NROW / AWPB, ABLOCK, 0, stream>>>(mem, ws_w, ws_i);
    gather_epilogue<<<NROW, BBLOCK, 0, stream>>>(src1, src2, ws_w, ws_i, out);
}

// Round 5
// 152.500 us; speedup vs baseline: 1.1150x; 1.1150x over previous
//
#include <hip/hip_runtime.h>
#include <math.h>

#define TOPK  20
#define NROW  4096
#define DDIM  256
#define NB    4
#define NCHUNK 16               // float4 chunks per lane (64 values/lane)

#define AWPB   2                // kernel A: waves (rows) per block
#define ABLOCK (AWPB * 64)
#define BBLOCK 256              // kernel B: 4 waves = 4 rows of one batch

typedef float vf4 __attribute__((ext_vector_type(4)));

__device__ __forceinline__ void wave_lds_fence() {
    asm volatile("s_waitcnt lgkmcnt(0)" ::: "memory");
}

__device__ __forceinline__ bool lex_gt(float av, int ai, float bv, int bi) {
    return (av > bv) || (av == bv && ai < bi);   // (value desc, index asc)
}

// bitonic sort of 64 (v,i) pairs across lanes, descending by lex key
__device__ __forceinline__ void bitonic64_desc(float& v, int& i, int lane) {
#pragma unroll
    for (int k = 2; k <= 64; k <<= 1) {
#pragma unroll
        for (int j = k >> 1; j > 0; j >>= 1) {
            float pv = __shfl_xor(v, j, 64);
            int   pi = __shfl_xor(i, j, 64);
            bool takeBig = ((lane & k) == 0) == ((lane & j) == 0);
            bool pBig = lex_gt(pv, pi, v, i);
            if (takeBig == pBig) { v = pv; i = pi; }
        }
    }
}

// ---------------- Kernel A: per-row softmax top-20 selection ----------------
__global__ __launch_bounds__(ABLOCK, 4) void topk_select(
    const float* __restrict__ mem,
    float* __restrict__ ws_w,
    int*   __restrict__ ws_i)
{
    __shared__ float cand_v[AWPB][64];
    __shared__ int   cand_i[AWPB][64];
    const int wave = threadIdx.x >> 6;
    const int lane = threadIdx.x & 63;
    const int n    = blockIdx.x * AWPB + wave;

    const float4* mrow = (const float4*)(mem + (size_t)n * NROW);
    float4 v4[NCHUNK];
#pragma unroll
    for (int j = 0; j < NCHUNK; ++j) v4[j] = mrow[lane + 64 * j];

    // per-lane top-1 (ascending index order -> strict > keeps lowest idx)
    float bv = -INFINITY; int bi = 0x7fffffff;
#pragma unroll
    for (int j = 0; j < NCHUNK; ++j) {
        const int base = 4 * lane + 256 * j;
        if (v4[j].x > bv) { bv = v4[j].x; bi = base + 0; }
        if (v4[j].y > bv) { bv = v4[j].y; bi = base + 1; }
        if (v4[j].z > bv) { bv = v4[j].z; bi = base + 2; }
        if (v4[j].w > bv) { bv = v4[j].w; bi = base + 3; }
    }

    // sort lane maxima: sorted[0] = row max, sorted[19] = threshold tau
    float sv = bv; int si = bi;
    bitonic64_desc(sv, si, lane);
    const float rowmax = __shfl(sv, 0, 64);
    const float tv     = __shfl(sv, 19, 64);
    const int   ti     = __shfl(si, 19, 64);

    float lsum = 0.f;
#pragma unroll
    for (int j = 0; j < NCHUNK; ++j) {
        lsum += __expf(v4[j].x - rowmax) + __expf(v4[j].y - rowmax)
              + __expf(v4[j].z - rowmax) + __expf(v4[j].w - rowmax);
    }
#pragma unroll
    for (int o = 32; o > 0; o >>= 1) lsum += __shfl_xor(lsum, o, 64);
    const float inv_denom = 1.0f / lsum;

    // count candidates >=lex (tv, ti); guaranteed >= 20 total
    int cnt = 0;
#pragma unroll
    for (int j = 0; j < NCHUNK; ++j) {
        const int base = 4 * lane + 256 * j;
        cnt += (v4[j].x > tv) || (v4[j].x == tv && (base + 0) <= ti);
        cnt += (v4[j].y > tv) || (v4[j].y == tv && (base + 1) <= ti);
        cnt += (v4[j].z > tv) || (v4[j].z == tv && (base + 2) <= ti);
        cnt += (v4[j].w > tv) || (v4[j].w == tv && (base + 3) <= ti);
    }
    int incl = cnt;
#pragma unroll
    for (int o = 1; o < 64; o <<= 1) {
        int t = __shfl_up(incl, o, 64);
        if (lane >= o) incl += t;
    }
    const int total = __builtin_amdgcn_readfirstlane(__shfl(incl, 63, 64));

    float* gw = ws_w + (size_t)n * TOPK;
    int*   gi = ws_i + (size_t)n * TOPK;

    if (total <= 64) {
        // FAST PATH: compact candidates to LDS (prefix-sum offsets), sort once
        int off = incl - cnt;
#pragma unroll
        for (int j = 0; j < NCHUNK; ++j) {
            const int base = 4 * lane + 256 * j;
            const float4 q = v4[j];
            if ((q.x > tv) || (q.x == tv && (base + 0) <= ti)) { cand_v[wave][off] = q.x; cand_i[wave][off] = base + 0; ++off; }
            if ((q.y > tv) || (q.y == tv && (base + 1) <= ti)) { cand_v[wave][off] = q.y; cand_i[wave][off] = base + 1; ++off; }
            if ((q.z > tv) || (q.z == tv && (base + 2) <= ti)) { cand_v[wave][off] = q.z; cand_i[wave][off] = base + 2; ++off; }
            if ((q.w > tv) || (q.w == tv && (base + 3) <= ti)) { cand_v[wave][off] = q.w; cand_i[wave][off] = base + 3; ++off; }
        }
        wave_lds_fence();
        float cv = -INFINITY; int ci = 0x7fffffff;
        if (lane < total) { cv = cand_v[wave][lane]; ci = cand_i[wave][lane]; }
        bitonic64_desc(cv, ci, lane);
        if (lane < TOPK) {
            gw[lane] = __expf(cv - rowmax) * inv_denom;
            gi[lane] = ci;
        }
    } else {
        // SLOW PATH (p ~ 0): 20 rounds of wave argmax extraction from regs
        unsigned long long dead = 0;
        float cv = bv; int ci = bi;
        for (int r = 0; r < TOPK; ++r) {
            float wv = cv; int wi = ci;
#pragma unroll
            for (int o = 32; o > 0; o >>= 1) {
                float ov = __shfl_xor(wv, o, 64);
                int   oi = __shfl_xor(wi, o, 64);
                if (lex_gt(ov, oi, wv, wi)) { wv = ov; wi = oi; }
            }
            if (lane == 0) {
                gw[r] = __expf(wv - rowmax) * inv_denom;
                gi[r] = wi;
            }
            if (ci == wi) {
                const int e = 4 * ((wi >> 8) & 15) + (wi & 3);
                dead |= (1ull << e);
                cv = -INFINITY; ci = 0x7fffffff;
#pragma unroll
                for (int j = 0; j < NCHUNK; ++j) {
                    const int base = 4 * lane + 256 * j;
                    if (!((dead >> (4 * j + 0)) & 1) && v4[j].x > cv) { cv = v4[j].x; ci = base + 0; }
                    if (!((dead >> (4 * j + 1)) & 1) && v4[j].y > cv) { cv = v4[j].y; ci = base + 1; }
                    if (!((dead >> (4 * j + 2)) & 1) && v4[j].z > cv) { cv = v4[j].z; ci = base + 2; }
                    if (!((dead >> (4 * j + 3)) & 1) && v4[j].w > cv) { cv = v4[j].w; ci = base + 3; }
                }
            }
        }
    }
}

// ---------------- Kernel B: gather epilogue, XCD-locality swizzled ----------------
// XCD = blockIdx % 8 (round-robin dispatch heuristic). Batch b = XCD/2, so each
// XCD's gathers hit only src2[b] (4 MiB = one XCD L2). src1/out use non-temporal
// accesses to avoid polluting L2. Swizzle affects only locality, not correctness.
__global__ __launch_bounds__(BBLOCK, 4) void gather_epilogue(
    const float* __restrict__ src1,
    const float* __restrict__ src2,
    const float* __restrict__ ws_w,
    const int*   __restrict__ ws_i,
    float* __restrict__ out)
{
    const int bid    = blockIdx.x;
    const int b      = (bid & 7) >> 1;                  // batch pinned per XCD pair
    const int ngroup = ((bid >> 3) << 1) | (bid & 1);   // 0..1023, covers all n/4
    const int wave   = threadIdx.x >> 6;
    const int lane   = threadIdx.x & 63;
    const int n      = ngroup * 4 + wave;

    const float* gw = ws_w + (size_t)n * TOPK;
    const int*   gi = ws_i + (size_t)n * TOPK;
    float wk[TOPK]; int ik[TOPK];
#pragma unroll
    for (int k = 0; k < TOPK; ++k) { wk[k] = gw[k]; ik[k] = gi[k]; }

    const vf4* s1  = (const vf4*)src1;
    const vf4* s2b = (const vf4*)src2 + (size_t)b * NROW * (DDIM / 4);
    vf4*       o4  = (vf4*)out;

    const size_t rowbase = ((size_t)b * NROW + n) * (DDIM / 4) + lane;
    vf4 acc = __builtin_nontemporal_load(s1 + rowbase);   // stream, don't cache
#pragma unroll
    for (int k = 0; k < TOPK; ++k) {
        const vf4 g = s2b[(size_t)ik[k] * (DDIM / 4) + lane];  // L2-resident gather
        acc += wk[k] * g;
    }
    __builtin_nontemporal_store(acc, o4 + rowbase);       // stream, don't cache
}

extern "C" void kernel_launch(void* const* d_in, const int* in_sizes, int n_in,
                              void* d_out, int out_size, void* d_ws, size_t ws_size,
                              hipStream_t stream) {
    const float* src1 = (const float*)d_in[0];   // [4, 4096, 256] f32
    const float* src2 = (const float*)d_in[1];   // [4, 4096, 256] f32
    const float* mem  = (const float*)d_in[2];   // [4096, 4096] f32
    float* out = (float*)d_out;                  // [4, 4096, 256] f32

    float* ws_w = (float*)d_ws;                      // 4096*20 floats
    int*   ws_i = (int*)d_ws + (size_t)NROW * TOPK;  // 4096*20 ints

    topk_select<<<NROW / AWPB, ABLOCK, 0, stream>>>(mem, ws_w, ws_i);
    gather_epilogue<<<NROW, BBLOCK, 0, stream>>>(src1, src2, ws_w, ws_i, out);
}